// Round 10
// baseline (160.724 us; speedup 1.0000x reference)
//
#include <hip/hip_runtime.h>

typedef __bf16 bf16;
typedef __bf16 bf16x4 __attribute__((ext_vector_type(4)));
typedef __bf16 bf16x8 __attribute__((ext_vector_type(8)));
typedef float f32x4 __attribute__((ext_vector_type(4)));
typedef float f32x16 __attribute__((ext_vector_type(16)));
typedef int i32x4 __attribute__((ext_vector_type(4)));

#define MFMA16(a, b, c) __builtin_amdgcn_mfma_f32_16x16x32_bf16((a), (b), (c), 0, 0, 0)
#define MFMA32(a, b, c) __builtin_amdgcn_mfma_f32_32x32x16_bf16((a), (b), (c), 0, 0, 0)

__device__ __forceinline__ int swz16(int r, int c) { return (c ^ (r & 15)); }

__device__ __forceinline__ int cvt_pk_bf16(float lo, float hi) {
  int r;
  asm("v_cvt_pk_bf16_f32 %0, %1, %2" : "=v"(r) : "v"(lo), "v"(hi));
  return r;
}

// ---- fused weight transposes: z=0..2 Wq/Wk/Wv (128x1024), z=3 Wo (1024x128) ----
__global__ __launch_bounds__(256) void trW_kernel(
    const float* __restrict__ Wq, const float* __restrict__ Wk,
    const float* __restrict__ Wv, const float* __restrict__ Wo,
    bf16* __restrict__ outbase) {
  __shared__ bf16 tile[32][33];
  const int z = blockIdx.z;
  const float* ib = (z == 0) ? Wq : (z == 1) ? Wk : (z == 2) ? Wv : Wo;
  bf16* ob = outbase + (size_t)z * 131072;
  const int R = (z < 3) ? 128 : 1024;
  const int C = (z < 3) ? 1024 : 128;
  int r0 = (z < 3) ? blockIdx.y * 32 : blockIdx.x * 32;
  int c0 = (z < 3) ? blockIdx.x * 32 : blockIdx.y * 32;
  int tx = threadIdx.x & 31, ty = threadIdx.x >> 5;
#pragma unroll
  for (int i = 0; i < 4; ++i) {
    int r = ty + i * 8;
    tile[r][tx] = (bf16)ib[(size_t)(r0 + r) * C + (c0 + tx)];
  }
  __syncthreads();
#pragma unroll
  for (int i = 0; i < 4; ++i) {
    int r = ty + i * 8;
    ob[(size_t)(c0 + r) * R + (r0 + tx)] = tile[tx][r];
  }
}

// -------- QKV projection -> fragment-major Q/K [blk32][sub16][hi][lane][8], V likewise
__global__ __launch_bounds__(256) void proj_gemm(
    const float* __restrict__ x, const bf16* __restrict__ Wqt,
    const bf16* __restrict__ Wkt, const bf16* __restrict__ Wvt,
    bf16* __restrict__ Qf, bf16* __restrict__ Kf, bf16* __restrict__ Vf) {
  __shared__ __align__(16) bf16 As[128 * 128];
  __shared__ __align__(16) bf16 Bs[128 * 128];
  const int mt = blockIdx.x;
  const int nt = blockIdx.y;
  const int matid = nt >> 3, h = nt & 7;
  const bf16* W = (matid == 0) ? Wqt : (matid == 1) ? Wkt : Wvt;
  const int tid = threadIdx.x;
  const bf16* sb = W + (size_t)h * 128 * 128;
#pragma unroll
  for (int i = 0; i < 8; ++i) {  // stage x tile, fp32 -> bf16
    int c = tid + i * 256;
    int r = c >> 4, cc = c & 15;
    const f32x4* p = (const f32x4*)(x + (size_t)(mt * 128 + r) * 128 + cc * 8);
    f32x4 a = p[0], b = p[1];
    bf16x8 o;
#pragma unroll
    for (int j = 0; j < 4; ++j) { o[j] = (bf16)a[j]; o[4 + j] = (bf16)b[j]; }
    *(bf16x8*)&As[r * 128 + swz16(r, cc) * 8] = o;
  }
#pragma unroll
  for (int i = 0; i < 8; ++i) {
    int c = tid + i * 256;
    int r = c >> 4, cc = c & 15;
    *(bf16x8*)&Bs[r * 128 + swz16(r, cc) * 8] = *(const bf16x8*)(sb + (size_t)r * 128 + cc * 8);
  }
  __syncthreads();
  const int wave = tid >> 6, lane = tid & 63;
  const int wr = (wave >> 1) * 64, wc = (wave & 1) * 64;
  const int lr = lane & 15, lkb = lane >> 4;
  const f32x4 FZ = {0.f, 0.f, 0.f, 0.f};
  f32x4 acc[4][4];
#pragma unroll
  for (int mf = 0; mf < 4; ++mf)
#pragma unroll
    for (int nf = 0; nf < 4; ++nf) acc[mf][nf] = FZ;
  const bool qk = (matid < 2);
#pragma unroll
  for (int ks = 0; ks < 4; ++ks) {
    bf16x8 a[4], b[4];
#pragma unroll
    for (int mf = 0; mf < 4; ++mf) {
      int r = wr + mf * 16 + lr;
      a[mf] = *(const bf16x8*)&As[r * 128 + swz16(r, ks * 4 + lkb) * 8];
    }
#pragma unroll
    for (int nf = 0; nf < 4; ++nf) {
      int r = wc + nf * 16 + lr;
      b[nf] = *(const bf16x8*)&Bs[r * 128 + swz16(r, ks * 4 + lkb) * 8];
    }
    if (qk) {  // transposed C: rows = d, cols = token
#pragma unroll
      for (int mf = 0; mf < 4; ++mf)
#pragma unroll
        for (int nf = 0; nf < 4; ++nf) acc[mf][nf] = MFMA16(b[nf], a[mf], acc[mf][nf]);
    } else {
#pragma unroll
      for (int mf = 0; mf < 4; ++mf)
#pragma unroll
        for (int nf = 0; nf < 4; ++nf) acc[mf][nf] = MFMA16(a[mf], b[nf], acc[mf][nf]);
    }
  }
  const int rb = lkb * 4;
  if (qk) {  // Q/K fragment-major: lane holds token m, 4 consecutive d
    bf16* Out = (matid == 0) ? Qf : Kf;
#pragma unroll
    for (int mf = 0; mf < 4; ++mf)
#pragma unroll
      for (int nf = 0; nf < 4; ++nf) {
        int m = mt * 128 + wr + mf * 16 + lr;
        int d0 = wc + nf * 16 + rb;
        int bb = m >> 11, t = m & 2047;
        bf16x4 vv;
#pragma unroll
        for (int r = 0; r < 4; ++r) vv[r] = (bf16)acc[mf][nf][r];
        size_t e = (size_t)(bb * 8 + h) * 262144
                 + (size_t)(((t >> 5) * 8 + (d0 >> 4)) * 512 + ((d0 >> 3) & 1) * 256
                            + (t & 31) * 8 + (d0 & 7));
        *(bf16x4*)(Out + e) = vv;
      }
  } else {  // V fragment-major: lane holds dim d, 4 consecutive tokens
#pragma unroll
    for (int mf = 0; mf < 4; ++mf)
#pragma unroll
      for (int nf = 0; nf < 4; ++nf) {
        int d = wc + nf * 16 + lr;
        int m0 = mt * 128 + wr + mf * 16 + rb;
        int bb = m0 >> 11, t0 = m0 & 2047;
        bf16x4 vv;
#pragma unroll
        for (int r = 0; r < 4; ++r) vv[r] = (bf16)acc[mf][nf][r];
        size_t e = (size_t)(bb * 8 + h) * 262144
                 + (size_t)((d >> 5) * 65536 + (t0 >> 4) * 512 + ((t0 >> 3) & 1) * 256
                            + (d & 31) * 8 + (t0 & 7));
        *(bf16x4*)(Vf + e) = vv;
      }
  }
}

// ---- causal flash attention: 1024 blocks x 4 waves; one (qt,bh) per block (LPT
// order), kv-split x4, LDS merge tree, split V-prefetch, 3 blocks/CU residency ----
__global__ __launch_bounds__(256, 3) void attn_kernel(
    bf16* __restrict__ Qf, const bf16* __restrict__ Kf, const bf16* __restrict__ Vf) {
  __shared__ float Om0[128 * 32];
  __shared__ float Om1[128 * 32];
  __shared__ float L0m[32], L0l[32], L1m[32], L1l[32];
  const int bid = blockIdx.x;
  const int bh = bid & 15;          // bid&7 -> XCD; 2 heads per XCD (K/V L2-resident)
  const int qt = 63 - (bid >> 4);   // LPT: biggest q-tiles dispatched first
  const int tid = threadIdx.x;
  const int w = tid >> 6, lane = tid & 63;
  const int lq = lane & 31, hi = lane >> 5;
  const int lo = hi * 256 + lq * 8;
  const bf16* Qh = Qf + (size_t)bh * 262144;
  const bf16* Kh = Kf + (size_t)bh * 262144;
  const bf16* Vh = Vf + (size_t)bh * 262144;
  const float SCL = 0.12751744f;    // log2(e)/sqrt(128)

  const int nT = (qt >> 1) + 1;
  const int base = nT >> 2, rem = nT & 3;
  const int cnt = base + (w < rem ? 1 : 0);
  const int tb = w * base + (w < rem ? w : rem);

  bf16x8 qf[8];
#pragma unroll
  for (int ks = 0; ks < 8; ++ks)
    qf[ks] = *(const bf16x8*)(Qh + qt * 4096 + ks * 512 + lo);

  float mrun = -__builtin_inff(), lrun = 0.f;
  f32x16 O[4];
#pragma unroll
  for (int dt = 0; dt < 4; ++dt)
#pragma unroll
    for (int r = 0; r < 16; ++r) O[dt][r] = 0.f;

  for (int it = 0; it < cnt; ++it) {
    const int kvt = tb + it;
    const int kv0 = kvt * 64;
    // ---- K fragments direct from L2 ----
    const bf16* kbase = Kh + kvt * 8192 + lo;
    bf16x8 ka[8], kb[8];
#pragma unroll
    for (int i = 0; i < 8; ++i) ka[i] = *(const bf16x8*)(kbase + i * 512);
#pragma unroll
    for (int i = 0; i < 8; ++i) kb[i] = *(const bf16x8*)(kbase + 4096 + i * 512);
    // ---- QK^T swapped: p[row=kv, col=q] ----
    f32x16 p0, p1;
#pragma unroll
    for (int r = 0; r < 16; ++r) { p0[r] = 0.f; p1[r] = 0.f; }
    __builtin_amdgcn_s_setprio(1);
#pragma unroll
    for (int ks = 0; ks < 8; ++ks) p0 = MFMA32(ka[ks], qf[ks], p0);
#pragma unroll
    for (int ks = 0; ks < 8; ++ks) p1 = MFMA32(kb[ks], qf[ks], p1);
    __builtin_amdgcn_s_setprio(0);
    // ---- first half of V (dt 0,1) issued now: latency hides under softmax ----
    const bf16* vbase = Vh + kvt * 2048 + lo;
    bf16x8 va[8];
#pragma unroll
    for (int i = 0; i < 8; ++i)
      va[i] = *(const bf16x8*)(vbase + (i >> 2) * 65536 + (i & 3) * 512);
    // ---- causal mask (diagonal tile only) ----
    if (kvt == (qt >> 1)) {
      const int qg = qt * 32 + lq;
#pragma unroll
      for (int r = 0; r < 16; ++r) {
        int kvr = kv0 + (r & 3) + 8 * (r >> 2) + 4 * hi;
        if (kvr > qg) p0[r] = -__builtin_inff();
        if (kvr + 32 > qg) p1[r] = -__builtin_inff();
      }
    }
    // ---- online softmax (tree-reduced, defer-max) ----
    float m0 = fmaxf(p0[0], p1[0]);
    float m1_ = fmaxf(p0[1], p1[1]);
    float m2 = fmaxf(p0[2], p1[2]);
    float m3 = fmaxf(p0[3], p1[3]);
#pragma unroll
    for (int r = 4; r < 16; r += 4) {
      m0 = fmaxf(m0, fmaxf(p0[r], p1[r]));
      m1_ = fmaxf(m1_, fmaxf(p0[r + 1], p1[r + 1]));
      m2 = fmaxf(m2, fmaxf(p0[r + 2], p1[r + 2]));
      m3 = fmaxf(m3, fmaxf(p0[r + 3], p1[r + 3]));
    }
    float pm = fmaxf(fmaxf(m0, m1_), fmaxf(m2, m3));
    pm = fmaxf(pm, __shfl_xor(pm, 32, 64));
    float pmS = pm * SCL;
    if (!__all(pmS <= mrun + 8.f)) {
      float mnew = fmaxf(mrun, pmS);
      float alpha = exp2f(mrun - mnew);
      mrun = mnew;
      lrun *= alpha;
#pragma unroll
      for (int dt = 0; dt < 4; ++dt)
#pragma unroll
        for (int r = 0; r < 16; ++r) O[dt][r] *= alpha;
    }
    float s0 = 0.f, s1 = 0.f, s2 = 0.f, s3 = 0.f;
#pragma unroll
    for (int r = 0; r < 16; r += 4) {
      float a0_ = exp2f(__builtin_fmaf(p0[r], SCL, -mrun));
      float a1_ = exp2f(__builtin_fmaf(p0[r + 1], SCL, -mrun));
      float a2_ = exp2f(__builtin_fmaf(p0[r + 2], SCL, -mrun));
      float a3_ = exp2f(__builtin_fmaf(p0[r + 3], SCL, -mrun));
      float b0_ = exp2f(__builtin_fmaf(p1[r], SCL, -mrun));
      float b1_ = exp2f(__builtin_fmaf(p1[r + 1], SCL, -mrun));
      float b2_ = exp2f(__builtin_fmaf(p1[r + 2], SCL, -mrun));
      float b3_ = exp2f(__builtin_fmaf(p1[r + 3], SCL, -mrun));
      p0[r] = a0_; p0[r + 1] = a1_; p0[r + 2] = a2_; p0[r + 3] = a3_;
      p1[r] = b0_; p1[r + 1] = b1_; p1[r + 2] = b2_; p1[r + 3] = b3_;
      s0 += a0_ + b0_; s1 += a1_ + b1_; s2 += a2_ + b2_; s3 += a3_ + b3_;
    }
    float ps = (s0 + s1) + (s2 + s3);
    ps += __shfl_xor(ps, 32, 64);
    lrun += ps;
    // ---- P -> bf16 B-frags in-register ----
    int wd[16];
#pragma unroll
    for (int i = 0; i < 8; ++i) wd[i] = cvt_pk_bf16(p0[2 * i], p0[2 * i + 1]);
#pragma unroll
    for (int i = 0; i < 8; ++i) wd[8 + i] = cvt_pk_bf16(p1[2 * i], p1[2 * i + 1]);
    bf16x8 pa[4];
#pragma unroll
    for (int t4 = 0; t4 < 4; ++t4) {
      int b0 = t4 * 4;
      int e0 = __shfl_xor(wd[b0 + 0], 32, 64);
      int e1 = __shfl_xor(wd[b0 + 1], 32, 64);
      int e2 = __shfl_xor(wd[b0 + 2], 32, 64);
      int e3 = __shfl_xor(wd[b0 + 3], 32, 64);
      i32x4 f;
      f[0] = hi ? e2 : wd[b0 + 0];
      f[1] = hi ? e3 : wd[b0 + 1];
      f[2] = hi ? wd[b0 + 2] : e0;
      f[3] = hi ? wd[b0 + 3] : e1;
      pa[t4] = __builtin_bit_cast(bf16x8, f);
    }
    // ---- second half of V (dt 2,3): flight time covered by PV dt0/dt1 ----
    bf16x8 vb[8];
#pragma unroll
    for (int i = 0; i < 8; ++i)
      vb[i] = *(const bf16x8*)(vbase + 131072 + (i >> 2) * 65536 + (i & 3) * 512);
    // ---- O^T += V^T @ P^T ----
    __builtin_amdgcn_s_setprio(1);
#pragma unroll
    for (int dt = 0; dt < 2; ++dt) {
      O[dt] = MFMA32(va[dt * 4 + 0], pa[0], O[dt]);
      O[dt] = MFMA32(va[dt * 4 + 1], pa[1], O[dt]);
      O[dt] = MFMA32(va[dt * 4 + 2], pa[2], O[dt]);
      O[dt] = MFMA32(va[dt * 4 + 3], pa[3], O[dt]);
    }
#pragma unroll
    for (int dt = 0; dt < 2; ++dt) {
      O[2 + dt] = MFMA32(vb[dt * 4 + 0], pa[0], O[2 + dt]);
      O[2 + dt] = MFMA32(vb[dt * 4 + 1], pa[1], O[2 + dt]);
      O[2 + dt] = MFMA32(vb[dt * 4 + 2], pa[2], O[2 + dt]);
      O[2 + dt] = MFMA32(vb[dt * 4 + 3], pa[3], O[2 + dt]);
    }
    __builtin_amdgcn_s_setprio(0);
  }

  // ---- 4-way merge tree via LDS ----
  auto STORE = [&](float* Om, float* Lm, float* Ll) {
#pragma unroll
    for (int dt = 0; dt < 4; ++dt)
#pragma unroll
      for (int r = 0; r < 16; ++r)
        Om[(dt * 32 + (r & 3) + 8 * (r >> 2) + 4 * hi) * 32 + lq] = O[dt][r];
    if (!hi) { Lm[lq] = mrun; Ll[lq] = lrun; }
  };
  auto MERGE = [&](const float* Om, const float* Lm, const float* Ll) {
    float m1 = Lm[lq], l1 = Ll[lq];
    float mF = fmaxf(mrun, m1);
    float a0 = (mrun < -3.0e38f) ? 0.f : exp2f(mrun - mF);
    float a1 = (m1 < -3.0e38f) ? 0.f : exp2f(m1 - mF);
    lrun = lrun * a0 + l1 * a1;
#pragma unroll
    for (int dt = 0; dt < 4; ++dt)
#pragma unroll
      for (int r = 0; r < 16; ++r)
        O[dt][r] = O[dt][r] * a0 +
                   Om[(dt * 32 + (r & 3) + 8 * (r >> 2) + 4 * hi) * 32 + lq] * a1;
    mrun = mF;
  };

  if (w == 1) STORE(Om0, L0m, L0l);
  if (w == 3) STORE(Om1, L1m, L1l);
  __syncthreads();
  if (w == 0) MERGE(Om0, L0m, L0l);
  if (w == 2) MERGE(Om1, L1m, L1l);
  __syncthreads();
  if (w == 2) STORE(Om0, L0m, L0l);
  __syncthreads();
  if (w == 0) {
    MERGE(Om0, L0m, L0l);
    float inv = 1.f / lrun;
    bf16* qw = Qf + (size_t)bh * 262144 + qt * 4096 + lq * 8 + 4 * hi;
#pragma unroll
    for (int dt = 0; dt < 4; ++dt) {
#pragma unroll
      for (int rq = 0; rq < 4; ++rq) {
        bf16x4 vv;
#pragma unroll
        for (int jj = 0; jj < 4; ++jj) {
          int r = rq * 4 + jj;
          vv[jj] = (bf16)(O[dt][r] * inv);
        }
        *(bf16x4*)(qw + (dt * 2 + (rq >> 1)) * 512 + (rq & 1) * 256) = vv;
      }
    }
  }
}

// ------- output projection: AO (fragment-major) @ Wot [128][1024] + bo -> fp32 out --
__global__ __launch_bounds__(256) void outproj_kernel(
    const bf16* __restrict__ AO, const bf16* __restrict__ Wot,
    const float* __restrict__ bo, float* __restrict__ out) {
  __shared__ __align__(16) bf16 As[16 * 128];
  __shared__ __align__(16) bf16 Bs[128 * 128];
  const f32x4 FZ = {0.f, 0.f, 0.f, 0.f};
  const int mt = blockIdx.x;  // 256 tiles of 16 rows
  const int tid = threadIdx.x, wave = tid >> 6, lane = tid & 63;
  const int lr = lane & 15, lkb = lane >> 4, rb = lkb * 4;
  const int wc = wave * 32;
  f32x4 acc[2];
  acc[0] = FZ; acc[1] = FZ;
  for (int kt = 0; kt < 8; ++kt) {  // kt == head index
    __syncthreads();
    {
      int r = tid >> 4, cc = tid & 15;
      int m = mt * 16 + r, bb = m >> 11, t = m & 2047;
      const bf16* src = AO + (size_t)(bb * 8 + kt) * 262144
          + ((t >> 5) * 8 + (cc >> 1)) * 512 + (cc & 1) * 256 + (t & 31) * 8;
      *(bf16x8*)&As[r * 128 + swz16(r, cc) * 8] = *(const bf16x8*)src;
    }
#pragma unroll
    for (int i = 0; i < 8; ++i) {
      int c = tid + i * 256;
      int r = c >> 4, cc = c & 15;
      *(bf16x8*)&Bs[r * 128 + swz16(r, cc) * 8] =
          *(const bf16x8*)(Wot + (size_t)r * 1024 + kt * 128 + cc * 8);
    }
    __syncthreads();
#pragma unroll
    for (int ks = 0; ks < 4; ++ks) {
      bf16x8 a = *(const bf16x8*)&As[lr * 128 + swz16(lr, ks * 4 + lkb) * 8];
#pragma unroll
      for (int nf = 0; nf < 2; ++nf) {
        int r = wc + nf * 16 + lr;
        bf16x8 b = *(const bf16x8*)&Bs[r * 128 + swz16(r, ks * 4 + lkb) * 8];
        acc[nf] = MFMA16(a, b, acc[nf]);
      }
    }
  }
#pragma unroll
  for (int nf = 0; nf < 2; ++nf)
#pragma unroll
    for (int r = 0; r < 4; ++r) {
      int m = mt * 16 + rb + r;
      int n = wc + nf * 16 + lr;
      out[(size_t)m * 128 + n] = acc[nf][r] + bo[n];
    }
}

extern "C" void kernel_launch(void* const* d_in, const int* in_sizes, int n_in,
                              void* d_out, int out_size, void* d_ws, size_t ws_size,
                              hipStream_t stream) {
  (void)in_sizes; (void)n_in; (void)out_size; (void)ws_size;
  const float* x  = (const float*)d_in[0];
  const float* Wq = (const float*)d_in[1];
  const float* Wk = (const float*)d_in[2];
  const float* Wv = (const float*)d_in[3];
  const float* Wo = (const float*)d_in[4];
  const float* bo = (const float*)d_in[5];
  float* out = (float*)d_out;

  bf16* ws  = (bf16*)d_ws;
  bf16* Wqt = ws;                 // [3][1024][128]
  bf16* Wkt = Wqt + 131072;
  bf16* Wvt = Wkt + 131072;
  bf16* Wot = Wvt + 131072;       // [128][1024]
  bf16* Qf  = Wot + 131072;       // [16] fragment-major Q; attn output in-place
  bf16* Kf  = Qf + 4194304;
  bf16* Vf  = Kf + 4194304;

  trW_kernel<<<dim3(32, 4, 4), 256, 0, stream>>>(Wq, Wk, Wv, Wo, Wqt);
  proj_gemm<<<dim3(32, 24, 1), 256, 0, stream>>>(x, Wqt, Wkt, Wvt, Qf, Kf, Vf);
  attn_kernel<<<dim3(1024, 1, 1), 256, 0, stream>>>(Qf, Kf, Vf);
  outproj_kernel<<<dim3(256, 1, 1), 256, 0, stream>>>(Qf, Wot, bo, out);
}